// Round 10
// baseline (262.779 us; speedup 1.0000x reference)
//
#include <hip/hip_runtime.h>
#include <math.h>

typedef __bf16 bf16;
typedef __bf16 bf16x8 __attribute__((ext_vector_type(8)));
typedef __bf16 bf16x4 __attribute__((ext_vector_type(4)));
typedef float  f32x4  __attribute__((ext_vector_type(4)));
typedef float  f32x16 __attribute__((ext_vector_type(16)));
typedef unsigned int u32;
typedef unsigned char u8;
typedef u32 u32x2 __attribute__((ext_vector_type(2)));
typedef u32 u32x4 __attribute__((ext_vector_type(4)));
typedef int  i32x8 __attribute__((ext_vector_type(8)));

#define MFMA(a, b, c)   __builtin_amdgcn_mfma_f32_16x16x32_bf16((a), (b), (c), 0, 0, 0)
// MX-scaled fp8 MFMA, 32x32x64, scales = 1.0 (e8m0 127 in every byte)
#define MFMAS(a, b, c)                                                           \
  __builtin_amdgcn_mfma_scale_f32_32x32x64_f8f6f4((a), (b), (c), 0, 0,           \
                                                  0, 0x7f7f7f7f, 0, 0x7f7f7f7f)

// async global->LDS, 16B per lane; LDS dest is wave-uniform base + lane*16
#define GLOAD_LDS16(g, l)                                                        \
  __builtin_amdgcn_global_load_lds(                                              \
      (const __attribute__((address_space(1))) void*)(g),                        \
      (__attribute__((address_space(3))) void*)(l), 16, 0, 0)

static constexpr int B_ = 8, C_ = 256, N_ = 4096;
// log2(e) / sqrt(C): folded into q.k scaling so softmax uses exp2 directly
static constexpr float QSCALE = 0.09016844005556021f;
static constexpr float PBIAS  = 2.0f;   // p = exp2(s - PBIAS); cancels in l-division

// R8 diagnostic: qkv ~50us @ MfmaUtil 10%, Occ 11% (latency-bound).  R9 freed
// registers (3-pass, 64-VGPR acc) but was NULL: grid was 512 blocks = exactly
// 2 blocks/CU -- occupancy was GRID-limited, launch_bounds couldn't help.
// R10: pass-split (Q/K/V = grid dim) + i-tile 64->32 => grid 3072, LDS 25 KB,
// VGPR cap 102 => 5 co-resident blocks/CU (5 waves/SIMD, 2.5x latency hiding).

// workspace layout (bytes).  zNum partial 0 REUSES the hT region (hT is dead
// after qkv_kernel); partial 1 lives at ZN2_OFF.
static constexpr size_t HT_OFF = 0;                    // hT [B][N][C] bf16 : 16.78 MB (-> zNum partial 0)
static constexpr size_t QT_OFF = 16777216;             // qT8 [B][N][C] fp8 : 8.39 MB
static constexpr size_t KT_OFF = 25165824;             // kT8 [B][N][C] fp8
static constexpr size_t V_OFF  = 33554432;             // v8  [B][C][N] fp8
static constexpr size_t WQ_OFF = 41943040;             // weights bf16, 128 KB each
static constexpr size_t WK_OFF = WQ_OFF + 131072;
static constexpr size_t WV_OFF = WK_OFF + 131072;
static constexpr size_t WO_OFF = WV_OFF + 131072;
static constexpr size_t LS_OFF = WO_OFF + 131072;      // lsum [2][B][N] f32 : 256 KB
static constexpr size_t ZN2_OFF = LS_OFF + 524288;     // zNum partial 1, 16.78 MB
static constexpr size_t PART_ELEMS = (size_t)B_ * C_ * N_;   // 8388608

// ---------------------------------------------------------------- groupnorm -> hT [B][N][C] bf16
// wconv fused in: first 256 threads also convert the 4 weight matrices.
__global__ __launch_bounds__(512) void gn_kernel(
    const float* __restrict__ x, const float* __restrict__ gsc, const float* __restrict__ gbi,
    bf16* __restrict__ hT,
    const float* __restrict__ wq, const float* __restrict__ wk,
    const float* __restrict__ wv, const float* __restrict__ wo,
    bf16* __restrict__ oq, bf16* __restrict__ ok, bf16* __restrict__ ov, bf16* __restrict__ oo) {
  int b = blockIdx.x >> 5, g = blockIdx.x & 31, c0 = g * 8;
  int t = threadIdx.x;
  if (t < 256) {                          // fused weight fp32->bf16 (65536 total)
    int i = blockIdx.x * 256 + t;
    oq[i] = (bf16)wq[i];
    ok[i] = (bf16)wk[i];
    ov[i] = (bf16)wv[i];
    oo[i] = (bf16)wo[i];
  }
  const float* base = x + ((size_t)(b * C_ + c0)) * N_;   // 8 channels * 4096, contiguous
  __shared__ bf16 xl[32768];    // 64 KB, channel-major [cc*4096 + i]
  float s = 0.f, ss = 0.f;
  const f32x4* b4 = (const f32x4*)base;
#pragma unroll
  for (int p = 0; p < 16; p++) {
    int u = t + p * 512;
    f32x4 v = b4[u];
    s  += v[0] + v[1] + v[2] + v[3];
    ss += v[0] * v[0] + v[1] * v[1] + v[2] * v[2] + v[3] * v[3];
    bf16x4 xv;
#pragma unroll
    for (int e = 0; e < 4; e++) xv[e] = (bf16)v[e];
    *(bf16x4*)(xl + u * 4) = xv;
  }
#pragma unroll
  for (int off = 1; off < 64; off <<= 1) {
    s  += __shfl_xor(s, off);
    ss += __shfl_xor(ss, off);
  }
  __shared__ float red[16];
  if ((t & 63) == 0) { red[(t >> 6) * 2] = s; red[(t >> 6) * 2 + 1] = ss; }
  __syncthreads();    // also publishes xl
  s = 0.f; ss = 0.f;
#pragma unroll
  for (int r = 0; r < 8; r++) { s += red[r * 2]; ss += red[r * 2 + 1]; }
  float mean = s * (1.f / 32768.f);
  float var  = ss * (1.f / 32768.f) - mean * mean;
  float rstd = rsqrtf(var + 1e-6f);
  float aa[8], bb[8];
#pragma unroll
  for (int cc = 0; cc < 8; cc++) {
    aa[cc] = rstd * gsc[c0 + cc];
    bb[cc] = gbi[c0 + cc] - mean * aa[cc];
  }
#pragma unroll
  for (int ii = 0; ii < 8; ii++) {
    int i = t + ii * 512;
    bf16x8 o;
#pragma unroll
    for (int cc = 0; cc < 8; cc++) o[cc] = (bf16)((float)xl[cc * 4096 + i] * aa[cc] + bb[cc]);
    *(bf16x8*)(hT + ((size_t)(b * N_ + i)) * C_ + c0) = o;  // 16B coalesced store
  }
}

// ---------------------------------------------------------------- QKV GEMMs (bf16 MFMA, fp8 outputs)
// R10: pass-parallel grid.  blk>>10 selects pass (0=Q,1=K,2=V); 1024 blocks
// per pass = 8 b x 128 i-tiles of 32 rows.  One 32-VGPR accumulator per wave;
// LDS = hl 16.9 KB + ep 8 KB = 25 KB -> 6 blocks/CU fit; launch_bounds(256,5)
// caps VGPR ~102 (floor ~70) -> 5 co-resident blocks/CU = 5 waves/SIMD.
// Epilogues via XOR-swizzled LDS transpose tile (coalesced stores, R7).
__global__ __launch_bounds__(256, 5) void qkv_kernel(
    const bf16* __restrict__ hT,
    const bf16* __restrict__ wqb, const bf16* __restrict__ wkb, const bf16* __restrict__ wvb,
    const float* __restrict__ bq, const float* __restrict__ bk, const float* __restrict__ bv,
    u8* __restrict__ qT8, u8* __restrict__ kT8, u8* __restrict__ v8) {
  int blk = blockIdx.x;
  int pass = blk >> 10;                   // 0=Q, 1=K, 2=V
  int bi = blk & 1023;
  int b = bi >> 7, i0 = (bi & 127) << 5;  // 32 i-rows per block
  int t = threadIdx.x, w = t >> 6, lane = t & 63, quad = lane >> 4, l15 = lane & 15;
  __shared__ bf16 hl[32 * 264];           // hT tile [32 i][256 c'], pad +8 (16.9 KB)
  __shared__ __align__(16) u8 ep[8192];   // transpose staging (8 KB)
  const bf16* wsel = (pass == 0) ? wqb : (pass == 1) ? wkb : wvb;

#pragma unroll
  for (int p = 0; p < 4; p++) {           // stage hT tile: 32 rows x 32 chunks
    int u = t + p * 256, r = u >> 5, c16 = u & 31;
    *(bf16x8*)(hl + r * 264 + c16 * 8) =
        *(const bf16x8*)(hT + ((size_t)(b * N_ + i0 + r)) * C_ + c16 * 8);
  }
  __syncthreads();
  int cw0 = w * 64;

  if (pass < 2) {
    // ---- Q/K: D rows = c_out, cols = i
    const float* bias = (pass == 0) ? bq : bk;
    float scale = (pass == 0) ? (QSCALE * 4.0f) : 0.25f;
    u8* outp = (pass == 0) ? qT8 : kT8;
    f32x4 acc[4][2];
#pragma unroll
    for (int a = 0; a < 4; a++)
#pragma unroll
      for (int bb2 = 0; bb2 < 2; bb2++) acc[a][bb2] = (f32x4){0.f, 0.f, 0.f, 0.f};
    for (int kc = 0; kc < 8; kc++) {
      bf16x8 hb[2];
#pragma unroll
      for (int it = 0; it < 2; it++)
        hb[it] = *(const bf16x8*)(hl + (it * 16 + l15) * 264 + kc * 32 + quad * 8);
#pragma unroll
      for (int ct = 0; ct < 4; ct++) {
        bf16x8 wf = *(const bf16x8*)(wsel + ((size_t)(cw0 + ct * 16 + l15)) * C_ + kc * 32 + quad * 8);
#pragma unroll
        for (int it = 0; it < 2; it++) acc[ct][it] = MFMA(wf, hb[it], acc[ct][it]);
      }
    }
    // epilogue: pack fp8 -> swizzled LDS [32 i][256 c] -> coalesced store
#pragma unroll
    for (int ct = 0; ct < 4; ct++)
#pragma unroll
      for (int it = 0; it < 2; it++) {
        int c4 = cw0 + ct * 16 + quad * 4;         // 4 consecutive c per lane
        int il = it * 16 + l15;
        f32x4 b4v = *(const f32x4*)(bias + c4);
        float qv[4];
#pragma unroll
        for (int r = 0; r < 4; r++) qv[r] = (acc[ct][it][r] + b4v[r]) * scale;
        u32 qd = (u32)__builtin_amdgcn_cvt_pk_fp8_f32(qv[0], qv[1], 0, false);
        qd = (u32)__builtin_amdgcn_cvt_pk_fp8_f32(qv[2], qv[3], (int)qd, true);
        *(u32*)(ep + il * 256 + ((((c4 >> 4) ^ (il & 15)) << 4) | (c4 & 12))) = qd;
      }
    __syncthreads();
#pragma unroll
    for (int p = 0; p < 2; p++) {        // 8 KB out, 16B/lane, rows contiguous
      int u = p * 256 + t, il = u >> 4, ch = u & 15;
      *(u32x4*)(outp + ((size_t)(b * N_ + i0 + il)) * C_ + ch * 16) =
          *(const u32x4*)(ep + il * 256 + (((ch ^ (il & 15)) << 4)));
    }
  } else {
    // ---- V: D rows = i, cols = c_out
    f32x4 acc[2][4];                      // acc[it][ct]
#pragma unroll
    for (int a = 0; a < 2; a++)
#pragma unroll
      for (int bb2 = 0; bb2 < 4; bb2++) acc[a][bb2] = (f32x4){0.f, 0.f, 0.f, 0.f};
    for (int kc = 0; kc < 8; kc++) {
      bf16x8 hb[2];
#pragma unroll
      for (int it = 0; it < 2; it++)
        hb[it] = *(const bf16x8*)(hl + (it * 16 + l15) * 264 + kc * 32 + quad * 8);
#pragma unroll
      for (int ct = 0; ct < 4; ct++) {
        bf16x8 wf = *(const bf16x8*)(wsel + ((size_t)(cw0 + ct * 16 + l15)) * C_ + kc * 32 + quad * 8);
#pragma unroll
        for (int it = 0; it < 2; it++) acc[it][ct] = MFMA(hb[it], wf, acc[it][ct]);
      }
    }
    // epilogue: pack fp8 -> swizzled LDS [256 c][32 i] -> 32B-segment store
#pragma unroll
    for (int it = 0; it < 2; it++)
#pragma unroll
      for (int ct = 0; ct < 4; ct++) {
        int cl = cw0 + ct * 16 + l15;
        float bvc = bv[cl];
        float vv4[4];
#pragma unroll
        for (int r = 0; r < 4; r++) vv4[r] = acc[it][ct][r] + bvc;
        u32 vd = (u32)__builtin_amdgcn_cvt_pk_fp8_f32(vv4[0], vv4[1], 0, false);
        vd = (u32)__builtin_amdgcn_cvt_pk_fp8_f32(vv4[2], vv4[3], (int)vd, true);
        *(u32*)(ep + cl * 32 + (((it ^ (cl & 1)) << 4) | (quad * 4))) = vd;
      }
    __syncthreads();
#pragma unroll
    for (int p = 0; p < 2; p++) {        // 8 KB out, 16B/lane, 32B c-row segments
      int u = p * 256 + t, cl = u >> 1, io = u & 1;
      *(u32x4*)(v8 + ((size_t)(b * C_ + cl)) * N_ + i0 + io * 16) =
          *(const u32x4*)(ep + cl * 32 + (((io ^ (cl & 1)) << 4)));
    }
  }
}

// ---------------------------------------------------------------- flash attention, fp8 MX MFMA 32x32x64, 64-key tiles, split-K=2
// FROZEN at R6 (82.5 us measured): T15 double-pipeline (PV delayed one tile),
// vmcnt(8) counted waits, permlane32 C->A, popcount stagger (neutral, kept).
// REGISTER BUDGET IS EXACTLY FULL: of[8]=128 AGPR + 128 VGPR = 256 unified
// regs/wave.  R5's extra cross-iteration state spilled (+15MB HBM, 128us);
// R3's (256,3) spilled of[] itself (1.98GB, 470us).
// SQ_LDS_BANK_CONFLICT ~= 16/DMA is structural to global_load_lds -- ignore.
__global__ __launch_bounds__(256, 2) void attn_kernel(
    const u8* __restrict__ qT8, const u8* __restrict__ kT8, const u8* __restrict__ v8,
    bf16* __restrict__ zn0, bf16* __restrict__ znR, float* __restrict__ lsum) {
  constexpr int NJT = 32;                 // 2048 keys / 64 per split
  int blk = blockIdx.x;
  int sp = blk >> 8;                      // 0..1 key split
  int b = blk & 7;                        // XCD-pinned batch
  int i0 = ((blk >> 3) & 31) << 7;        // 128 q-rows per block
  int t = threadIdx.x, w = t >> 6, lane = t & 63;
  int r31 = lane & 31, h = lane >> 5;
  __shared__ __align__(16) u8 lds8[4 * 16384];  // kb0 | kb1 | vb0 | vb1

  int iw = i0 + w * 32;                   // this wave's 32 query rows
  // Q as B-frag (col i = r31, k = c, 32B per MFMA)
  const u8* qrow = qT8 + ((size_t)(b * N_ + iw + r31)) * C_ + h * 32;
  i32x8 qB[4];
#pragma unroll
  for (int m = 0; m < 4; m++) qB[m] = *(const i32x8*)(qrow + m * 64);

  f32x16 of[8];
#pragma unroll
  for (int ct = 0; ct < 8; ct++)
#pragma unroll
    for (int e = 0; e < 16; e++) of[ct][e] = 0.f;
  float lacc = 0.f;

  int ks = r31 & 7;                       // K-read swizzle
  // DMA lane decode (loop-invariant)
  int kr_off = lane >> 4;                 // row within K issue (4 rows/KB)
  int kc_pos = lane & 15;                 // dest chunk
  int vr_off = lane >> 2;                 // row within V issue (16 rows/KB)
  int vc_pos = lane & 3;
  int spBase = sp * 2048;

  auto stageK = [&](int jts, u8* kb) {
    int j0s = spBase + jts * 64;
#pragma unroll
    for (int p = 0; p < 4; p++) {         // kT: 16 x 1KB issues, 4 per wave
      int idx = w * 4 + p;
      int r = idx * 4 + kr_off;
      int chunk = kc_pos ^ (r & 7);
      GLOAD_LDS16(kT8 + ((size_t)(b * N_ + j0s + r)) * C_ + chunk * 16, kb + idx * 1024);
    }
  };
  auto stageV = [&](int jts, u8* vb) {
    int j0s = spBase + jts * 64;
#pragma unroll
    for (int p = 0; p < 4; p++) {         // v: 16 x 1KB issues, 4 per wave
      int idx = w * 4 + p;
      int c = idx * 16 + vr_off;
      int chunk = vc_pos ^ ((c >> 1) & 3);
      GLOAD_LDS16(v8 + ((size_t)(b * C_ + c)) * N_ + j0s + chunk * 16, vb + idx * 1024);
    }
  };

  stageK(0, lds8);                        // prologue: K(0), V(0) in flight
  stageV(0, lds8 + 32768);

  // anti-phase stagger (measured neutral, kept): odd-popcount blocks start late
  if (__popc(blk) & 1) __builtin_amdgcn_s_sleep(48);   // ~3072 cyc

  i32x8 pPrev;                            // fp8-packed P of tile jt-1

  for (int jt = 0; jt < NJT; jt++) {
    stageK(jt < NJT - 1 ? jt + 1 : jt, lds8 + (((jt + 1) & 1) << 14));
    asm volatile("s_waitcnt vmcnt(8)" ::: "memory");  // own K(jt) landed
    __builtin_amdgcn_s_barrier();         // B: everyone's K(jt) + V(jt-1) in LDS
    const u8* kTl = lds8 + ((jt & 1) << 14);
    const u8* vbp = lds8 + 32768 + (((jt + 1) & 1) << 14);  // vb[(jt-1)&1]

    // ---- QK^T g0: S^T rows j=r31, C-init = -PBIAS
    f32x16 st0;
#pragma unroll
    for (int e = 0; e < 16; e++) st0[e] = -PBIAS;
    {
      const u8* krow = kTl + r31 * 256;
      __builtin_amdgcn_s_setprio(1);
#pragma unroll
      for (int m = 0; m < 4; m++) {
        int cd = m * 4 + h * 2;
        union { i32x8 v; u32x4 h4[2]; } kf;
        kf.h4[0] = *(const u32x4*)(krow + ((cd ^ ks) * 16));
        kf.h4[1] = *(const u32x4*)(krow + (((cd + 1) ^ ks) * 16));
        st0 = MFMAS(kf.v, qB[m], st0);
      }
    }
    // ---- PV(jt-1): independent of st0 chain & softmax -> fills matrix pipe
    if (jt) {
#pragma unroll
      for (int ct = 0; ct < 8; ct++) {
        int c = ct * 32 + r31;
        int vs = (c >> 1) & 3;
        const u8* vrow = vbp + c * 64;
        union { i32x8 v; u32x4 h4[2]; } vB;
        vB.h4[0] = *(const u32x4*)(vrow + (((2 * h) ^ vs) * 16));
        vB.h4[1] = *(const u32x4*)(vrow + (((2 * h + 1) ^ vs) * 16));
        of[ct] = MFMAS(pPrev, vB.v, of[ct]);
      }
    }
    __builtin_amdgcn_s_setprio(0);
    // ---- softmax g0 (runs while PV MFMAs crunch)
    u32 PG0[4], PG1[4];
#pragma unroll
    for (int b4 = 0; b4 < 4; b4++) {
      float p0 = __builtin_amdgcn_exp2f(st0[b4 * 4 + 0]);
      float p1 = __builtin_amdgcn_exp2f(st0[b4 * 4 + 1]);
      float p2 = __builtin_amdgcn_exp2f(st0[b4 * 4 + 2]);
      float p3 = __builtin_amdgcn_exp2f(st0[b4 * 4 + 3]);
      lacc += (p0 + p1) + (p2 + p3);
      u32 d = (u32)__builtin_amdgcn_cvt_pk_fp8_f32(p0, p1, 0, false);
      d = (u32)__builtin_amdgcn_cvt_pk_fp8_f32(p2, p3, (int)d, true);
      PG0[b4] = d;
    }
    // ---- QK^T g1
    f32x16 st1;
#pragma unroll
    for (int e = 0; e < 16; e++) st1[e] = -PBIAS;
    {
      const u8* krow = kTl + (32 + r31) * 256;
      __builtin_amdgcn_s_setprio(1);
#pragma unroll
      for (int m = 0; m < 4; m++) {
        int cd = m * 4 + h * 2;
        union { i32x8 v; u32x4 h4[2]; } kf;
        kf.h4[0] = *(const u32x4*)(krow + ((cd ^ ks) * 16));
        kf.h4[1] = *(const u32x4*)(krow + (((cd + 1) ^ ks) * 16));
        st1 = MFMAS(kf.v, qB[m], st1);
      }
      __builtin_amdgcn_s_setprio(0);
    }
    // ---- softmax g1
#pragma unroll
    for (int b4 = 0; b4 < 4; b4++) {
      float p0 = __builtin_amdgcn_exp2f(st1[b4 * 4 + 0]);
      float p1 = __builtin_amdgcn_exp2f(st1[b4 * 4 + 1]);
      float p2 = __builtin_amdgcn_exp2f(st1[b4 * 4 + 2]);
      float p3 = __builtin_amdgcn_exp2f(st1[b4 * 4 + 3]);
      lacc += (p0 + p1) + (p2 + p3);
      u32 d = (u32)__builtin_amdgcn_cvt_pk_fp8_f32(p0, p1, 0, false);
      d = (u32)__builtin_amdgcn_cvt_pk_fp8_f32(p2, p3, (int)d, true);
      PG1[b4] = d;
    }
    // ---- C->A exchange into pPrev (old pPrev already consumed by PV above)
    // permlane32_swap(PG0, PG1):
    //   rr[0]: lanes<32 own PG0 (j=8b4+0..3)    | lanes>=32 partner PG1 (j=32+8b4+0..3)
    //   rr[1]: lanes<32 partner PG0 (j=8b4+4..7)| lanes>=32 own PG1 (j=32+8b4+4..7)
#pragma unroll
    for (int b4 = 0; b4 < 4; b4++) {
      u32x2 rr = __builtin_amdgcn_permlane32_swap(PG0[b4], PG1[b4], false, false);
      pPrev[2 * b4]     = (int)rr[0];
      pPrev[2 * b4 + 1] = (int)rr[1];
    }

    __builtin_amdgcn_s_barrier();         // C: all reads of kb[jt&1], vb[(jt-1)&1] done
    if (jt < NJT - 1) stageV(jt + 1, lds8 + 32768 + (((jt + 1) & 1) << 14));
  }

  // ---- epilogue: final PV(NJT-1)
  asm volatile("s_waitcnt vmcnt(0)" ::: "memory");
  __builtin_amdgcn_s_barrier();           // everyone's V(NJT-1) landed
  {
    const u8* vbp = lds8 + 32768 + (((NJT - 1) & 1) << 14);
#pragma unroll
    for (int ct = 0; ct < 8; ct++) {
      int c = ct * 32 + r31;
      int vs = (c >> 1) & 3;
      const u8* vrow = vbp + c * 64;
      union { i32x8 v; u32x4 h4[2]; } vB;
      vB.h4[0] = *(const u32x4*)(vrow + (((2 * h) ^ vs) * 16));
      vB.h4[1] = *(const u32x4*)(vrow + (((2 * h + 1) ^ vs) * 16));
      of[ct] = MFMAS(pPrev, vB.v, of[ct]);
    }
  }

  // ---- write partials: zNum [sp][b][c][i] bf16, lsum [sp][b][i] f32
  lacc += __shfl_xor(lacc, 32);           // full key-split sum (once per kernel)
  if (h == 0)
    lsum[((size_t)(sp * 8 + b)) * N_ + iw + r31] = lacc;
  bf16* zn = (sp == 0) ? zn0 : znR;
#pragma unroll
  for (int ct = 0; ct < 8; ct++) {
    int c = ct * 32 + r31;
#pragma unroll
    for (int g = 0; g < 4; g++) {
      bf16x4 zv;
#pragma unroll
      for (int e = 0; e < 4; e++) zv[e] = (bf16)of[ct][g * 4 + e];
      int i4 = iw + 8 * g + 4 * h;        // rows i = e + 8g + 4h
      *(bf16x4*)(zn + ((size_t)(b * C_ + c)) * N_ + i4) = zv;  // 8B packed
    }
  }
}

// ---------------------------------------------------------------- combine partials + O-proj + bias + skip
// zl pad 266: staging writes 2-way banked; GEMM reads conflict-free.
__global__ __launch_bounds__(256) void combine_kernel(
    const bf16* __restrict__ zn0, const bf16* __restrict__ znR,
    const float* __restrict__ lsum,
    const bf16* __restrict__ wob, const float* __restrict__ bo,
    const float* __restrict__ x, float* __restrict__ out) {
  int b = blockIdx.x >> 6, i0 = (blockIdx.x & 63) << 6;
  int t = threadIdx.x, w = t >> 6, lane = t & 63, quad = lane >> 4, l15 = lane & 15;
  __shared__ bf16 zl[64 * 266];         // zT tile [64 i][256 c], pad +10
  __shared__ float linv[64];

  if (t < 64) {
    size_t ii = (size_t)b * N_ + i0 + t;
    linv[t] = 1.f / (lsum[ii] + lsum[ii + (size_t)8 * N_]);
  }
  __syncthreads();

#pragma unroll
  for (int p = 0; p < 16; p++) {        // 256 c x 16 i4-chunks; coalesced 8B reads
    int u = t + p * 256, c = u >> 4, ii = (u & 15) * 4;
    size_t base = ((size_t)(b * C_ + c)) * N_ + i0 + ii;
    bf16x4 z0 = *(const bf16x4*)(zn0 + base);
    bf16x4 z1 = *(const bf16x4*)(znR + base);
#pragma unroll
    for (int e = 0; e < 4; e++)
      zl[(ii + e) * 266 + c] = (bf16)(((float)z0[e] + (float)z1[e]) * linv[ii + e]);
  }
  __syncthreads();

  f32x4 oa[4][4];
#pragma unroll
  for (int a = 0; a < 4; a++)
#pragma unroll
    for (int bb2 = 0; bb2 < 4; bb2++) oa[a][bb2] = (f32x4){0.f, 0.f, 0.f, 0.f};
  for (int kc = 0; kc < 8; kc++) {
    bf16x8 za[4];
#pragma unroll
    for (int it = 0; it < 4; it++)
      za[it] = *(const bf16x8*)(zl + (it * 16 + l15) * 266 + kc * 32 + quad * 8);
#pragma unroll
    for (int ctl = 0; ctl < 4; ctl++) {
      bf16x8 wf = *(const bf16x8*)(wob + ((size_t)(w * 64 + ctl * 16 + l15)) * C_ + kc * 32 + quad * 8);
#pragma unroll
      for (int it = 0; it < 4; it++) oa[ctl][it] = MFMA(za[it], wf, oa[ctl][it]);
    }
  }
#pragma unroll
  for (int ctl = 0; ctl < 4; ctl++)
#pragma unroll
    for (int it = 0; it < 4; it++) {
      int c = w * 64 + ctl * 16 + l15;
      size_t base = ((size_t)(b * C_ + c)) * N_ + i0 + it * 16 + quad * 4;
      f32x4 xs = *(const f32x4*)(x + base);
      float boc = bo[c];
      f32x4 o4;
#pragma unroll
      for (int r = 0; r < 4; r++) o4[r] = oa[ctl][it][r] + boc + xs[r];
      *(f32x4*)(out + base) = o4;     // coalesced 16B fp32 store, skip fused
    }
}

// ---------------------------------------------------------------- launch
extern "C" void kernel_launch(void* const* d_in, const int* in_sizes, int n_in,
                              void* d_out, int out_size, void* d_ws, size_t ws_size,
                              hipStream_t stream) {
  const float* x   = (const float*)d_in[0];
  const float* gsc = (const float*)d_in[1];
  const float* gbi = (const float*)d_in[2];
  const float* wq  = (const float*)d_in[3];
  const float* bq  = (const float*)d_in[4];
  const float* wk  = (const float*)d_in[5];
  const float* bk  = (const float*)d_in[6];
  const float* wv  = (const float*)d_in[7];
  const float* bv  = (const float*)d_in[8];
  const float* wo  = (const float*)d_in[9];
  const float* bo  = (const float*)d_in[10];

  char* ws = (char*)d_ws;
  bf16* hT   = (bf16*)(ws + HT_OFF);
  u8*   qT8  = (u8*)(ws + QT_OFF);
  u8*   kT8  = (u8*)(ws + KT_OFF);
  u8*   v8   = (u8*)(ws + V_OFF);
  bf16* wqb  = (bf16*)(ws + WQ_OFF);
  bf16* wkb  = (bf16*)(ws + WK_OFF);
  bf16* wvb  = (bf16*)(ws + WV_OFF);
  bf16* wob  = (bf16*)(ws + WO_OFF);
  float* lsum = (float*)(ws + LS_OFF);
  bf16* zn0  = (bf16*)(ws + HT_OFF);     // partial 0 reuses hT (dead after qkv)
  bf16* znR  = (bf16*)(ws + ZN2_OFF);    // partial 1

  gn_kernel<<<256, 512, 0, stream>>>(x, gsc, gbi, hT, wq, wk, wv, wo, wqb, wkb, wvb, wob);
  qkv_kernel<<<3072, 256, 0, stream>>>(hT, wqb, wkb, wvb, bq, bk, bv, qT8, kT8, v8);
  attn_kernel<<<512, 256, 0, stream>>>(qT8, kT8, v8, zn0, znR, lsum);
  combine_kernel<<<512, 256, 0, stream>>>(zn0, znR, lsum, wob, bo, x, (float*)d_out);
}

// Round 11
// 257.300 us; speedup vs baseline: 1.0213x; 1.0213x over previous
//
#include <hip/hip_runtime.h>
#include <math.h>

typedef __bf16 bf16;
typedef __bf16 bf16x8 __attribute__((ext_vector_type(8)));
typedef __bf16 bf16x4 __attribute__((ext_vector_type(4)));
typedef float  f32x4  __attribute__((ext_vector_type(4)));
typedef float  f32x16 __attribute__((ext_vector_type(16)));
typedef unsigned int u32;
typedef unsigned char u8;
typedef u32 u32x2 __attribute__((ext_vector_type(2)));
typedef u32 u32x4 __attribute__((ext_vector_type(4)));
typedef int  i32x8 __attribute__((ext_vector_type(8)));

#define MFMA(a, b, c)   __builtin_amdgcn_mfma_f32_16x16x32_bf16((a), (b), (c), 0, 0, 0)
// MX-scaled fp8 MFMA, 32x32x64, scales = 1.0 (e8m0 127 in every byte)
#define MFMAS(a, b, c)                                                           \
  __builtin_amdgcn_mfma_scale_f32_32x32x64_f8f6f4((a), (b), (c), 0, 0,           \
                                                  0, 0x7f7f7f7f, 0, 0x7f7f7f7f)

// async global->LDS, 16B per lane; LDS dest is wave-uniform base + lane*16
#define GLOAD_LDS16(g, l)                                                        \
  __builtin_amdgcn_global_load_lds(                                              \
      (const __attribute__((address_space(1))) void*)(g),                        \
      (__attribute__((address_space(3))) void*)(l), 16, 0, 0)

static constexpr int B_ = 8, C_ = 256, N_ = 4096;
// log2(e) / sqrt(C): folded into q.k scaling so softmax uses exp2 directly
static constexpr float QSCALE = 0.09016844005556021f;
static constexpr float PBIAS  = 2.0f;   // p = exp2(s - PBIAS); cancels in l-division

// qkv history: R8 diag ~50us @ MfmaUtil 10%, Occ 11% (latency-bound, 2 blk/CU,
// GRID-limited).  R9 (3 seq passes, 64-VGPR acc, grid 512): null (-1.8us) --
// grid still 512.  R10 (pass-split grid 3072, short blocks): REGRESSED +21us
// (3x hT reads, prologue per 64 MFMAs).  R11: keep R9's 3-pass long blocks
// (hT staged once / 192 MFMAs), i-tile 64->32 => grid 1024 = 4 blk/CU supply;
// LDS 25 KB, launch_bounds(256,4) caps VGPR 128 (pass floor ~80, no spill).

// workspace layout (bytes).  zNum partial 0 REUSES the hT region (hT is dead
// after qkv_kernel); partial 1 lives at ZN2_OFF.
static constexpr size_t HT_OFF = 0;                    // hT [B][N][C] bf16 : 16.78 MB (-> zNum partial 0)
static constexpr size_t QT_OFF = 16777216;             // qT8 [B][N][C] fp8 : 8.39 MB
static constexpr size_t KT_OFF = 25165824;             // kT8 [B][N][C] fp8
static constexpr size_t V_OFF  = 33554432;             // v8  [B][C][N] fp8
static constexpr size_t WQ_OFF = 41943040;             // weights bf16, 128 KB each
static constexpr size_t WK_OFF = WQ_OFF + 131072;
static constexpr size_t WV_OFF = WK_OFF + 131072;
static constexpr size_t WO_OFF = WV_OFF + 131072;
static constexpr size_t LS_OFF = WO_OFF + 131072;      // lsum [2][B][N] f32 : 256 KB
static constexpr size_t ZN2_OFF = LS_OFF + 524288;     // zNum partial 1, 16.78 MB
static constexpr size_t PART_ELEMS = (size_t)B_ * C_ * N_;   // 8388608

// ---------------------------------------------------------------- groupnorm -> hT [B][N][C] bf16
// wconv fused in: first 256 threads also convert the 4 weight matrices.
__global__ __launch_bounds__(512) void gn_kernel(
    const float* __restrict__ x, const float* __restrict__ gsc, const float* __restrict__ gbi,
    bf16* __restrict__ hT,
    const float* __restrict__ wq, const float* __restrict__ wk,
    const float* __restrict__ wv, const float* __restrict__ wo,
    bf16* __restrict__ oq, bf16* __restrict__ ok, bf16* __restrict__ ov, bf16* __restrict__ oo) {
  int b = blockIdx.x >> 5, g = blockIdx.x & 31, c0 = g * 8;
  int t = threadIdx.x;
  if (t < 256) {                          // fused weight fp32->bf16 (65536 total)
    int i = blockIdx.x * 256 + t;
    oq[i] = (bf16)wq[i];
    ok[i] = (bf16)wk[i];
    ov[i] = (bf16)wv[i];
    oo[i] = (bf16)wo[i];
  }
  const float* base = x + ((size_t)(b * C_ + c0)) * N_;   // 8 channels * 4096, contiguous
  __shared__ bf16 xl[32768];    // 64 KB, channel-major [cc*4096 + i]
  float s = 0.f, ss = 0.f;
  const f32x4* b4 = (const f32x4*)base;
#pragma unroll
  for (int p = 0; p < 16; p++) {
    int u = t + p * 512;
    f32x4 v = b4[u];
    s  += v[0] + v[1] + v[2] + v[3];
    ss += v[0] * v[0] + v[1] * v[1] + v[2] * v[2] + v[3] * v[3];
    bf16x4 xv;
#pragma unroll
    for (int e = 0; e < 4; e++) xv[e] = (bf16)v[e];
    *(bf16x4*)(xl + u * 4) = xv;
  }
#pragma unroll
  for (int off = 1; off < 64; off <<= 1) {
    s  += __shfl_xor(s, off);
    ss += __shfl_xor(ss, off);
  }
  __shared__ float red[16];
  if ((t & 63) == 0) { red[(t >> 6) * 2] = s; red[(t >> 6) * 2 + 1] = ss; }
  __syncthreads();    // also publishes xl
  s = 0.f; ss = 0.f;
#pragma unroll
  for (int r = 0; r < 8; r++) { s += red[r * 2]; ss += red[r * 2 + 1]; }
  float mean = s * (1.f / 32768.f);
  float var  = ss * (1.f / 32768.f) - mean * mean;
  float rstd = rsqrtf(var + 1e-6f);
  float aa[8], bb[8];
#pragma unroll
  for (int cc = 0; cc < 8; cc++) {
    aa[cc] = rstd * gsc[c0 + cc];
    bb[cc] = gbi[c0 + cc] - mean * aa[cc];
  }
#pragma unroll
  for (int ii = 0; ii < 8; ii++) {
    int i = t + ii * 512;
    bf16x8 o;
#pragma unroll
    for (int cc = 0; cc < 8; cc++) o[cc] = (bf16)((float)xl[cc * 4096 + i] * aa[cc] + bb[cc]);
    *(bf16x8*)(hT + ((size_t)(b * N_ + i)) * C_ + c0) = o;  // 16B coalesced store
  }
}

// ---------------------------------------------------------------- QKV GEMMs (bf16 MFMA, fp8 outputs)
// R11: R9's 3-sequential-pass structure (one 32-VGPR-class accumulator live at
// a time; hT staged ONCE per block and reused by all 3 passes) at i-tile 32 ->
// grid 1024 = 4 blocks/CU supply.  LDS: hl 16.9 KB + ep 8 KB = 25 KB.
// Epilogues via XOR-swizzled LDS transpose tile (coalesced stores, R7).
__global__ __launch_bounds__(256, 4) void qkv_kernel(
    const bf16* __restrict__ hT,
    const bf16* __restrict__ wqb, const bf16* __restrict__ wkb, const bf16* __restrict__ wvb,
    const float* __restrict__ bq, const float* __restrict__ bk, const float* __restrict__ bv,
    u8* __restrict__ qT8, u8* __restrict__ kT8, u8* __restrict__ v8) {
  int blk = blockIdx.x;
  int b = blk >> 7, i0 = (blk & 127) << 5;   // 32 i-rows per block
  int t = threadIdx.x, w = t >> 6, lane = t & 63, quad = lane >> 4, l15 = lane & 15;
  __shared__ bf16 hl[32 * 264];           // hT tile [32 i][256 c'], pad +8 (16.9 KB)
  __shared__ __align__(16) u8 ep[8192];   // transpose staging, reused Q -> K -> V

#pragma unroll
  for (int p = 0; p < 4; p++) {           // stage hT tile: 32 rows x 32 chunks
    int u = t + p * 256, r = u >> 5, c16 = u & 31;
    *(bf16x8*)(hl + r * 264 + c16 * 8) =
        *(const bf16x8*)(hT + ((size_t)(b * N_ + i0 + r)) * C_ + c16 * 8);
  }
  __syncthreads();
  int cw0 = w * 64;

  // ================= PASS Q: D rows = c_out, cols = i =================
  {
    f32x4 acc[4][2];
#pragma unroll
    for (int a = 0; a < 4; a++)
#pragma unroll
      for (int bb2 = 0; bb2 < 2; bb2++) acc[a][bb2] = (f32x4){0.f, 0.f, 0.f, 0.f};
    for (int kc = 0; kc < 8; kc++) {
      bf16x8 hb[2];
#pragma unroll
      for (int it = 0; it < 2; it++)
        hb[it] = *(const bf16x8*)(hl + (it * 16 + l15) * 264 + kc * 32 + quad * 8);
#pragma unroll
      for (int ct = 0; ct < 4; ct++) {
        bf16x8 wf = *(const bf16x8*)(wqb + ((size_t)(cw0 + ct * 16 + l15)) * C_ + kc * 32 + quad * 8);
#pragma unroll
        for (int it = 0; it < 2; it++) acc[ct][it] = MFMA(wf, hb[it], acc[ct][it]);
      }
    }
    // epilogue: pack fp8 -> swizzled LDS [32 i][256 c] -> coalesced store
#pragma unroll
    for (int ct = 0; ct < 4; ct++)
#pragma unroll
      for (int it = 0; it < 2; it++) {
        int c4 = cw0 + ct * 16 + quad * 4;         // 4 consecutive c per lane
        int il = it * 16 + l15;
        f32x4 b4v = *(const f32x4*)(bq + c4);
        float qv[4];
#pragma unroll
        for (int r = 0; r < 4; r++) qv[r] = (acc[ct][it][r] + b4v[r]) * (QSCALE * 4.0f);
        u32 qd = (u32)__builtin_amdgcn_cvt_pk_fp8_f32(qv[0], qv[1], 0, false);
        qd = (u32)__builtin_amdgcn_cvt_pk_fp8_f32(qv[2], qv[3], (int)qd, true);
        *(u32*)(ep + il * 256 + ((((c4 >> 4) ^ (il & 15)) << 4) | (c4 & 12))) = qd;
      }
    __syncthreads();
#pragma unroll
    for (int p = 0; p < 2; p++) {        // 8 KB out, 16B/lane, rows contiguous
      int u = p * 256 + t, il = u >> 4, ch = u & 15;
      *(u32x4*)(qT8 + ((size_t)(b * N_ + i0 + il)) * C_ + ch * 16) =
          *(const u32x4*)(ep + il * 256 + (((ch ^ (il & 15)) << 4)));
    }
    __syncthreads();
  }

  // ================= PASS K: D rows = c_out, cols = i =================
  {
    f32x4 acc[4][2];
#pragma unroll
    for (int a = 0; a < 4; a++)
#pragma unroll
      for (int bb2 = 0; bb2 < 2; bb2++) acc[a][bb2] = (f32x4){0.f, 0.f, 0.f, 0.f};
    for (int kc = 0; kc < 8; kc++) {
      bf16x8 hb[2];
#pragma unroll
      for (int it = 0; it < 2; it++)
        hb[it] = *(const bf16x8*)(hl + (it * 16 + l15) * 264 + kc * 32 + quad * 8);
#pragma unroll
      for (int ct = 0; ct < 4; ct++) {
        bf16x8 wf = *(const bf16x8*)(wkb + ((size_t)(cw0 + ct * 16 + l15)) * C_ + kc * 32 + quad * 8);
#pragma unroll
        for (int it = 0; it < 2; it++) acc[ct][it] = MFMA(wf, hb[it], acc[ct][it]);
      }
    }
#pragma unroll
    for (int ct = 0; ct < 4; ct++)
#pragma unroll
      for (int it = 0; it < 2; it++) {
        int c4 = cw0 + ct * 16 + quad * 4;
        int il = it * 16 + l15;
        f32x4 b4v = *(const f32x4*)(bk + c4);
        float kv[4];
#pragma unroll
        for (int r = 0; r < 4; r++) kv[r] = (acc[ct][it][r] + b4v[r]) * 0.25f;
        u32 kd = (u32)__builtin_amdgcn_cvt_pk_fp8_f32(kv[0], kv[1], 0, false);
        kd = (u32)__builtin_amdgcn_cvt_pk_fp8_f32(kv[2], kv[3], (int)kd, true);
        *(u32*)(ep + il * 256 + ((((c4 >> 4) ^ (il & 15)) << 4) | (c4 & 12))) = kd;
      }
    __syncthreads();
#pragma unroll
    for (int p = 0; p < 2; p++) {
      int u = p * 256 + t, il = u >> 4, ch = u & 15;
      *(u32x4*)(kT8 + ((size_t)(b * N_ + i0 + il)) * C_ + ch * 16) =
          *(const u32x4*)(ep + il * 256 + (((ch ^ (il & 15)) << 4)));
    }
  }

  // ================= PASS V: D rows = i, cols = c_out =================
  {
    f32x4 acc[2][4];                      // acc[it][ct]
#pragma unroll
    for (int a = 0; a < 2; a++)
#pragma unroll
      for (int bb2 = 0; bb2 < 4; bb2++) acc[a][bb2] = (f32x4){0.f, 0.f, 0.f, 0.f};
    for (int kc = 0; kc < 8; kc++) {
      bf16x8 hb[2];
#pragma unroll
      for (int it = 0; it < 2; it++)
        hb[it] = *(const bf16x8*)(hl + (it * 16 + l15) * 264 + kc * 32 + quad * 8);
#pragma unroll
      for (int ct = 0; ct < 4; ct++) {
        bf16x8 wf = *(const bf16x8*)(wvb + ((size_t)(cw0 + ct * 16 + l15)) * C_ + kc * 32 + quad * 8);
#pragma unroll
        for (int it = 0; it < 2; it++) acc[it][ct] = MFMA(hb[it], wf, acc[it][ct]);
      }
    }
    __syncthreads();                      // all K readouts of ep done
    // epilogue: pack fp8 -> swizzled LDS [256 c][32 i] -> 32B-segment store
#pragma unroll
    for (int it = 0; it < 2; it++)
#pragma unroll
      for (int ct = 0; ct < 4; ct++) {
        int cl = cw0 + ct * 16 + l15;
        float bvc = bv[cl];
        float vv4[4];
#pragma unroll
        for (int r = 0; r < 4; r++) vv4[r] = acc[it][ct][r] + bvc;
        u32 vd = (u32)__builtin_amdgcn_cvt_pk_fp8_f32(vv4[0], vv4[1], 0, false);
        vd = (u32)__builtin_amdgcn_cvt_pk_fp8_f32(vv4[2], vv4[3], (int)vd, true);
        *(u32*)(ep + cl * 32 + (((it ^ (cl & 1)) << 4) | (quad * 4))) = vd;
      }
    __syncthreads();
#pragma unroll
    for (int p = 0; p < 2; p++) {        // 8 KB out, 16B/lane, 32B c-row segments
      int u = p * 256 + t, cl = u >> 1, io = u & 1;
      *(u32x4*)(v8 + ((size_t)(b * C_ + cl)) * N_ + i0 + io * 16) =
          *(const u32x4*)(ep + cl * 32 + (((io ^ (cl & 1)) << 4)));
    }
  }
}

// ---------------------------------------------------------------- flash attention, fp8 MX MFMA 32x32x64, 64-key tiles, split-K=2
// FROZEN at R6 (82.5 us measured): T15 double-pipeline (PV delayed one tile),
// vmcnt(8) counted waits, permlane32 C->A, popcount stagger (neutral, kept).
// REGISTER BUDGET IS EXACTLY FULL: of[8]=128 AGPR + 128 VGPR = 256 unified
// regs/wave.  R5's extra cross-iteration state spilled (+15MB HBM, 128us);
// R3's (256,3) spilled of[] itself (1.98GB, 470us).
// SQ_LDS_BANK_CONFLICT ~= 16/DMA is structural to global_load_lds -- ignore.
__global__ __launch_bounds__(256, 2) void attn_kernel(
    const u8* __restrict__ qT8, const u8* __restrict__ kT8, const u8* __restrict__ v8,
    bf16* __restrict__ zn0, bf16* __restrict__ znR, float* __restrict__ lsum) {
  constexpr int NJT = 32;                 // 2048 keys / 64 per split
  int blk = blockIdx.x;
  int sp = blk >> 8;                      // 0..1 key split
  int b = blk & 7;                        // XCD-pinned batch
  int i0 = ((blk >> 3) & 31) << 7;        // 128 q-rows per block
  int t = threadIdx.x, w = t >> 6, lane = t & 63;
  int r31 = lane & 31, h = lane >> 5;
  __shared__ __align__(16) u8 lds8[4 * 16384];  // kb0 | kb1 | vb0 | vb1

  int iw = i0 + w * 32;                   // this wave's 32 query rows
  // Q as B-frag (col i = r31, k = c, 32B per MFMA)
  const u8* qrow = qT8 + ((size_t)(b * N_ + iw + r31)) * C_ + h * 32;
  i32x8 qB[4];
#pragma unroll
  for (int m = 0; m < 4; m++) qB[m] = *(const i32x8*)(qrow + m * 64);

  f32x16 of[8];
#pragma unroll
  for (int ct = 0; ct < 8; ct++)
#pragma unroll
    for (int e = 0; e < 16; e++) of[ct][e] = 0.f;
  float lacc = 0.f;

  int ks = r31 & 7;                       // K-read swizzle
  // DMA lane decode (loop-invariant)
  int kr_off = lane >> 4;                 // row within K issue (4 rows/KB)
  int kc_pos = lane & 15;                 // dest chunk
  int vr_off = lane >> 2;                 // row within V issue (16 rows/KB)
  int vc_pos = lane & 3;
  int spBase = sp * 2048;

  auto stageK = [&](int jts, u8* kb) {
    int j0s = spBase + jts * 64;
#pragma unroll
    for (int p = 0; p < 4; p++) {         // kT: 16 x 1KB issues, 4 per wave
      int idx = w * 4 + p;
      int r = idx * 4 + kr_off;
      int chunk = kc_pos ^ (r & 7);
      GLOAD_LDS16(kT8 + ((size_t)(b * N_ + j0s + r)) * C_ + chunk * 16, kb + idx * 1024);
    }
  };
  auto stageV = [&](int jts, u8* vb) {
    int j0s = spBase + jts * 64;
#pragma unroll
    for (int p = 0; p < 4; p++) {         // v: 16 x 1KB issues, 4 per wave
      int idx = w * 4 + p;
      int c = idx * 16 + vr_off;
      int chunk = vc_pos ^ ((c >> 1) & 3);
      GLOAD_LDS16(v8 + ((size_t)(b * C_ + c)) * N_ + j0s + chunk * 16, vb + idx * 1024);
    }
  };

  stageK(0, lds8);                        // prologue: K(0), V(0) in flight
  stageV(0, lds8 + 32768);

  // anti-phase stagger (measured neutral, kept): odd-popcount blocks start late
  if (__popc(blk) & 1) __builtin_amdgcn_s_sleep(48);   // ~3072 cyc

  i32x8 pPrev;                            // fp8-packed P of tile jt-1

  for (int jt = 0; jt < NJT; jt++) {
    stageK(jt < NJT - 1 ? jt + 1 : jt, lds8 + (((jt + 1) & 1) << 14));
    asm volatile("s_waitcnt vmcnt(8)" ::: "memory");  // own K(jt) landed
    __builtin_amdgcn_s_barrier();         // B: everyone's K(jt) + V(jt-1) in LDS
    const u8* kTl = lds8 + ((jt & 1) << 14);
    const u8* vbp = lds8 + 32768 + (((jt + 1) & 1) << 14);  // vb[(jt-1)&1]

    // ---- QK^T g0: S^T rows j=r31, C-init = -PBIAS
    f32x16 st0;
#pragma unroll
    for (int e = 0; e < 16; e++) st0[e] = -PBIAS;
    {
      const u8* krow = kTl + r31 * 256;
      __builtin_amdgcn_s_setprio(1);
#pragma unroll
      for (int m = 0; m < 4; m++) {
        int cd = m * 4 + h * 2;
        union { i32x8 v; u32x4 h4[2]; } kf;
        kf.h4[0] = *(const u32x4*)(krow + ((cd ^ ks) * 16));
        kf.h4[1] = *(const u32x4*)(krow + (((cd + 1) ^ ks) * 16));
        st0 = MFMAS(kf.v, qB[m], st0);
      }
    }
    // ---- PV(jt-1): independent of st0 chain & softmax -> fills matrix pipe
    if (jt) {
#pragma unroll
      for (int ct = 0; ct < 8; ct++) {
        int c = ct * 32 + r31;
        int vs = (c >> 1) & 3;
        const u8* vrow = vbp + c * 64;
        union { i32x8 v; u32x4 h4[2]; } vB;
        vB.h4[0] = *(const u32x4*)(vrow + (((2 * h) ^ vs) * 16));
        vB.h4[1] = *(const u32x4*)(vrow + (((2 * h + 1) ^ vs) * 16));
        of[ct] = MFMAS(pPrev, vB.v, of[ct]);
      }
    }
    __builtin_amdgcn_s_setprio(0);
    // ---- softmax g0 (runs while PV MFMAs crunch)
    u32 PG0[4], PG1[4];
#pragma unroll
    for (int b4 = 0; b4 < 4; b4++) {
      float p0 = __builtin_amdgcn_exp2f(st0[b4 * 4 + 0]);
      float p1 = __builtin_amdgcn_exp2f(st0[b4 * 4 + 1]);
      float p2 = __builtin_amdgcn_exp2f(st0[b4 * 4 + 2]);
      float p3 = __builtin_amdgcn_exp2f(st0[b4 * 4 + 3]);
      lacc += (p0 + p1) + (p2 + p3);
      u32 d = (u32)__builtin_amdgcn_cvt_pk_fp8_f32(p0, p1, 0, false);
      d = (u32)__builtin_amdgcn_cvt_pk_fp8_f32(p2, p3, (int)d, true);
      PG0[b4] = d;
    }
    // ---- QK^T g1
    f32x16 st1;
#pragma unroll
    for (int e = 0; e < 16; e++) st1[e] = -PBIAS;
    {
      const u8* krow = kTl + (32 + r31) * 256;
      __builtin_amdgcn_s_setprio(1);
#pragma unroll
      for (int m = 0; m < 4; m++) {
        int cd = m * 4 + h * 2;
        union { i32x8 v; u32x4 h4[2]; } kf;
        kf.h4[0] = *(const u32x4*)(krow + ((cd ^ ks) * 16));
        kf.h4[1] = *(const u32x4*)(krow + (((cd + 1) ^ ks) * 16));
        st1 = MFMAS(kf.v, qB[m], st1);
      }
      __builtin_amdgcn_s_setprio(0);
    }
    // ---- softmax g1
#pragma unroll
    for (int b4 = 0; b4 < 4; b4++) {
      float p0 = __builtin_amdgcn_exp2f(st1[b4 * 4 + 0]);
      float p1 = __builtin_amdgcn_exp2f(st1[b4 * 4 + 1]);
      float p2 = __builtin_amdgcn_exp2f(st1[b4 * 4 + 2]);
      float p3 = __builtin_amdgcn_exp2f(st1[b4 * 4 + 3]);
      lacc += (p0 + p1) + (p2 + p3);
      u32 d = (u32)__builtin_amdgcn_cvt_pk_fp8_f32(p0, p1, 0, false);
      d = (u32)__builtin_amdgcn_cvt_pk_fp8_f32(p2, p3, (int)d, true);
      PG1[b4] = d;
    }
    // ---- C->A exchange into pPrev (old pPrev already consumed by PV above)
    // permlane32_swap(PG0, PG1):
    //   rr[0]: lanes<32 own PG0 (j=8b4+0..3)    | lanes>=32 partner PG1 (j=32+8b4+0..3)
    //   rr[1]: lanes<32 partner PG0 (j=8b4+4..7)| lanes>=32 own PG1 (j=32+8b4+4..7)
#pragma unroll
    for (int b4 = 0; b4 < 4; b4++) {
      u32x2 rr = __builtin_amdgcn_permlane32_swap(PG0[b4], PG1[b4], false, false);
      pPrev[2 * b4]     = (int)rr[0];
      pPrev[2 * b4 + 1] = (int)rr[1];
    }

    __builtin_amdgcn_s_barrier();         // C: all reads of kb[jt&1], vb[(jt-1)&1] done
    if (jt < NJT - 1) stageV(jt + 1, lds8 + 32768 + (((jt + 1) & 1) << 14));
  }

  // ---- epilogue: final PV(NJT-1)
  asm volatile("s_waitcnt vmcnt(0)" ::: "memory");
  __builtin_amdgcn_s_barrier();           // everyone's V(NJT-1) landed
  {
    const u8* vbp = lds8 + 32768 + (((NJT - 1) & 1) << 14);
#pragma unroll
    for (int ct = 0; ct < 8; ct++) {
      int c = ct * 32 + r31;
      int vs = (c >> 1) & 3;
      const u8* vrow = vbp + c * 64;
      union { i32x8 v; u32x4 h4[2]; } vB;
      vB.h4[0] = *(const u32x4*)(vrow + (((2 * h) ^ vs) * 16));
      vB.h4[1] = *(const u32x4*)(vrow + (((2 * h + 1) ^ vs) * 16));
      of[ct] = MFMAS(pPrev, vB.v, of[ct]);
    }
  }

  // ---- write partials: zNum [sp][b][c][i] bf16, lsum [sp][b][i] f32
  lacc += __shfl_xor(lacc, 32);           // full key-split sum (once per kernel)
  if (h == 0)
    lsum[((size_t)(sp * 8 + b)) * N_ + iw + r31] = lacc;
  bf16* zn = (sp == 0) ? zn0 : znR;
#pragma unroll
  for (int ct = 0; ct < 8; ct++) {
    int c = ct * 32 + r31;
#pragma unroll
    for (int g = 0; g < 4; g++) {
      bf16x4 zv;
#pragma unroll
      for (int e = 0; e < 4; e++) zv[e] = (bf16)of[ct][g * 4 + e];
      int i4 = iw + 8 * g + 4 * h;        // rows i = e + 8g + 4h
      *(bf16x4*)(zn + ((size_t)(b * C_ + c)) * N_ + i4) = zv;  // 8B packed
    }
  }
}

// ---------------------------------------------------------------- combine partials + O-proj + bias + skip
// zl pad 266: staging writes 2-way banked; GEMM reads conflict-free.
__global__ __launch_bounds__(256) void combine_kernel(
    const bf16* __restrict__ zn0, const bf16* __restrict__ znR,
    const float* __restrict__ lsum,
    const bf16* __restrict__ wob, const float* __restrict__ bo,
    const float* __restrict__ x, float* __restrict__ out) {
  int b = blockIdx.x >> 6, i0 = (blockIdx.x & 63) << 6;
  int t = threadIdx.x, w = t >> 6, lane = t & 63, quad = lane >> 4, l15 = lane & 15;
  __shared__ bf16 zl[64 * 266];         // zT tile [64 i][256 c], pad +10
  __shared__ float linv[64];

  if (t < 64) {
    size_t ii = (size_t)b * N_ + i0 + t;
    linv[t] = 1.f / (lsum[ii] + lsum[ii + (size_t)8 * N_]);
  }
  __syncthreads();

#pragma unroll
  for (int p = 0; p < 16; p++) {        // 256 c x 16 i4-chunks; coalesced 8B reads
    int u = t + p * 256, c = u >> 4, ii = (u & 15) * 4;
    size_t base = ((size_t)(b * C_ + c)) * N_ + i0 + ii;
    bf16x4 z0 = *(const bf16x4*)(zn0 + base);
    bf16x4 z1 = *(const bf16x4*)(znR + base);
#pragma unroll
    for (int e = 0; e < 4; e++)
      zl[(ii + e) * 266 + c] = (bf16)(((float)z0[e] + (float)z1[e]) * linv[ii + e]);
  }
  __syncthreads();

  f32x4 oa[4][4];
#pragma unroll
  for (int a = 0; a < 4; a++)
#pragma unroll
    for (int bb2 = 0; bb2 < 4; bb2++) oa[a][bb2] = (f32x4){0.f, 0.f, 0.f, 0.f};
  for (int kc = 0; kc < 8; kc++) {
    bf16x8 za[4];
#pragma unroll
    for (int it = 0; it < 4; it++)
      za[it] = *(const bf16x8*)(zl + (it * 16 + l15) * 266 + kc * 32 + quad * 8);
#pragma unroll
    for (int ctl = 0; ctl < 4; ctl++) {
      bf16x8 wf = *(const bf16x8*)(wob + ((size_t)(w * 64 + ctl * 16 + l15)) * C_ + kc * 32 + quad * 8);
#pragma unroll
      for (int it = 0; it < 4; it++) oa[ctl][it] = MFMA(za[it], wf, oa[ctl][it]);
    }
  }
#pragma unroll
  for (int ctl = 0; ctl < 4; ctl++)
#pragma unroll
    for (int it = 0; it < 4; it++) {
      int c = w * 64 + ctl * 16 + l15;
      size_t base = ((size_t)(b * C_ + c)) * N_ + i0 + it * 16 + quad * 4;
      f32x4 xs = *(const f32x4*)(x + base);
      float boc = bo[c];
      f32x4 o4;
#pragma unroll
      for (int r = 0; r < 4; r++) o4[r] = oa[ctl][it][r] + boc + xs[r];
      *(f32x4*)(out + base) = o4;     // coalesced 16B fp32 store, skip fused
    }
}

// ---------------------------------------------------------------- launch
extern "C" void kernel_launch(void* const* d_in, const int* in_sizes, int n_in,
                              void* d_out, int out_size, void* d_ws, size_t ws_size,
                              hipStream_t stream) {
  const float* x   = (const float*)d_in[0];
  const float* gsc = (const float*)d_in[1];
  const float* gbi = (const float*)d_in[2];
  const float* wq  = (const float*)d_in[3];
  const float* bq  = (const float*)d_in[4];
  const float* wk  = (const float*)d_in[5];
  const float* bk  = (const float*)d_in[6];
  const float* wv  = (const float*)d_in[7];
  const float* bv  = (const float*)d_in[8];
  const float* wo  = (const float*)d_in[9];
  const float* bo  = (const float*)d_in[10];

  char* ws = (char*)d_ws;
  bf16* hT   = (bf16*)(ws + HT_OFF);
  u8*   qT8  = (u8*)(ws + QT_OFF);
  u8*   kT8  = (u8*)(ws + KT_OFF);
  u8*   v8   = (u8*)(ws + V_OFF);
  bf16* wqb  = (bf16*)(ws + WQ_OFF);
  bf16* wkb  = (bf16*)(ws + WK_OFF);
  bf16* wvb  = (bf16*)(ws + WV_OFF);
  bf16* wob  = (bf16*)(ws + WO_OFF);
  float* lsum = (float*)(ws + LS_OFF);
  bf16* zn0  = (bf16*)(ws + HT_OFF);     // partial 0 reuses hT (dead after qkv)
  bf16* znR  = (bf16*)(ws + ZN2_OFF);    // partial 1

  gn_kernel<<<256, 512, 0, stream>>>(x, gsc, gbi, hT, wq, wk, wv, wo, wqb, wkb, wvb, wob);
  qkv_kernel<<<1024, 256, 0, stream>>>(hT, wqb, wkb, wvb, bq, bk, bv, qT8, kT8, v8);
  attn_kernel<<<512, 256, 0, stream>>>(qT8, kT8, v8, zn0, znR, lsum);
  combine_kernel<<<512, 256, 0, stream>>>(zn0, znR, lsum, wob, bo, x, (float*)d_out);
}

// Round 12
// 239.041 us; speedup vs baseline: 1.0993x; 1.0764x over previous
//
#include <hip/hip_runtime.h>
#include <math.h>

typedef __bf16 bf16;
typedef __bf16 bf16x8 __attribute__((ext_vector_type(8)));
typedef __bf16 bf16x4 __attribute__((ext_vector_type(4)));
typedef float  f32x4  __attribute__((ext_vector_type(4)));
typedef float  f32x16 __attribute__((ext_vector_type(16)));
typedef unsigned int u32;
typedef unsigned char u8;
typedef u32 u32x2 __attribute__((ext_vector_type(2)));
typedef u32 u32x4 __attribute__((ext_vector_type(4)));
typedef int  i32x8 __attribute__((ext_vector_type(8)));

#define MFMA(a, b, c)   __builtin_amdgcn_mfma_f32_16x16x32_bf16((a), (b), (c), 0, 0, 0)
// MX-scaled fp8 MFMA, 32x32x64, scales = 1.0 (e8m0 127 in every byte)
#define MFMAS(a, b, c)                                                           \
  __builtin_amdgcn_mfma_scale_f32_32x32x64_f8f6f4((a), (b), (c), 0, 0,           \
                                                  0, 0x7f7f7f7f, 0, 0x7f7f7f7f)

// async global->LDS, 16B per lane; LDS dest is wave-uniform base + lane*16
#define GLOAD_LDS16(g, l)                                                        \
  __builtin_amdgcn_global_load_lds(                                              \
      (const __attribute__((address_space(1))) void*)(g),                        \
      (__attribute__((address_space(3))) void*)(l), 16, 0, 0)

static constexpr int B_ = 8, C_ = 256, N_ = 4096;
// log2(e) / sqrt(C): folded into q.k scaling so softmax uses exp2 directly
static constexpr float QSCALE = 0.09016844005556021f;
static constexpr float PBIAS  = 2.0f;   // p = exp2(s - PBIAS); cancels in l-division

// qkv history: R8 diag ~50us @ MfmaUtil 10% (latency-bound).  R9 (3 seq
// passes, 64-reg acc, grid 512) = best total 241.7.  R10 (pass-split grid
// 3072) REGRESSED +21 (3x hT reads, short blocks).  R11 (i-tile 32, grid
// 1024) REGRESSED +16 (2x weight reads, halved amortization).  Conclusion:
// per-block-work shrinkage costs more than occupancy recovers -- qkv tiling
// is at a local optimum.  R12 = R9 + #pragma unroll 2 on kc loops (lets the
// scheduler hoist iter k+1's weight loads above iter k's MFMAs; the rolled
// loop serialized a ~200cyc L2 load stall per iteration).

// workspace layout (bytes).  zNum partial 0 REUSES the hT region (hT is dead
// after qkv_kernel); partial 1 lives at ZN2_OFF.
static constexpr size_t HT_OFF = 0;                    // hT [B][N][C] bf16 : 16.78 MB (-> zNum partial 0)
static constexpr size_t QT_OFF = 16777216;             // qT8 [B][N][C] fp8 : 8.39 MB
static constexpr size_t KT_OFF = 25165824;             // kT8 [B][N][C] fp8
static constexpr size_t V_OFF  = 33554432;             // v8  [B][C][N] fp8
static constexpr size_t WQ_OFF = 41943040;             // weights bf16, 128 KB each
static constexpr size_t WK_OFF = WQ_OFF + 131072;
static constexpr size_t WV_OFF = WK_OFF + 131072;
static constexpr size_t WO_OFF = WV_OFF + 131072;
static constexpr size_t LS_OFF = WO_OFF + 131072;      // lsum [2][B][N] f32 : 256 KB
static constexpr size_t ZN2_OFF = LS_OFF + 524288;     // zNum partial 1, 16.78 MB
static constexpr size_t PART_ELEMS = (size_t)B_ * C_ * N_;   // 8388608

// ---------------------------------------------------------------- groupnorm -> hT [B][N][C] bf16
// wconv fused in: first 256 threads also convert the 4 weight matrices.
__global__ __launch_bounds__(512) void gn_kernel(
    const float* __restrict__ x, const float* __restrict__ gsc, const float* __restrict__ gbi,
    bf16* __restrict__ hT,
    const float* __restrict__ wq, const float* __restrict__ wk,
    const float* __restrict__ wv, const float* __restrict__ wo,
    bf16* __restrict__ oq, bf16* __restrict__ ok, bf16* __restrict__ ov, bf16* __restrict__ oo) {
  int b = blockIdx.x >> 5, g = blockIdx.x & 31, c0 = g * 8;
  int t = threadIdx.x;
  if (t < 256) {                          // fused weight fp32->bf16 (65536 total)
    int i = blockIdx.x * 256 + t;
    oq[i] = (bf16)wq[i];
    ok[i] = (bf16)wk[i];
    ov[i] = (bf16)wv[i];
    oo[i] = (bf16)wo[i];
  }
  const float* base = x + ((size_t)(b * C_ + c0)) * N_;   // 8 channels * 4096, contiguous
  __shared__ bf16 xl[32768];    // 64 KB, channel-major [cc*4096 + i]
  float s = 0.f, ss = 0.f;
  const f32x4* b4 = (const f32x4*)base;
#pragma unroll
  for (int p = 0; p < 16; p++) {
    int u = t + p * 512;
    f32x4 v = b4[u];
    s  += v[0] + v[1] + v[2] + v[3];
    ss += v[0] * v[0] + v[1] * v[1] + v[2] * v[2] + v[3] * v[3];
    bf16x4 xv;
#pragma unroll
    for (int e = 0; e < 4; e++) xv[e] = (bf16)v[e];
    *(bf16x4*)(xl + u * 4) = xv;
  }
#pragma unroll
  for (int off = 1; off < 64; off <<= 1) {
    s  += __shfl_xor(s, off);
    ss += __shfl_xor(ss, off);
  }
  __shared__ float red[16];
  if ((t & 63) == 0) { red[(t >> 6) * 2] = s; red[(t >> 6) * 2 + 1] = ss; }
  __syncthreads();    // also publishes xl
  s = 0.f; ss = 0.f;
#pragma unroll
  for (int r = 0; r < 8; r++) { s += red[r * 2]; ss += red[r * 2 + 1]; }
  float mean = s * (1.f / 32768.f);
  float var  = ss * (1.f / 32768.f) - mean * mean;
  float rstd = rsqrtf(var + 1e-6f);
  float aa[8], bb[8];
#pragma unroll
  for (int cc = 0; cc < 8; cc++) {
    aa[cc] = rstd * gsc[c0 + cc];
    bb[cc] = gbi[c0 + cc] - mean * aa[cc];
  }
#pragma unroll
  for (int ii = 0; ii < 8; ii++) {
    int i = t + ii * 512;
    bf16x8 o;
#pragma unroll
    for (int cc = 0; cc < 8; cc++) o[cc] = (bf16)((float)xl[cc * 4096 + i] * aa[cc] + bb[cc]);
    *(bf16x8*)(hT + ((size_t)(b * N_ + i)) * C_ + c0) = o;  // 16B coalesced store
  }
}

// ---------------------------------------------------------------- QKV GEMMs (bf16 MFMA, fp8 outputs)
// R12 = R9's 3-sequential-pass structure (one 64-VGPR accumulator live at a
// time; hT staged once, reused by all 3 passes; grid 512, i-tile 64) with
// #pragma unroll 2 on the kc loops for load/MFMA software pipelining.
// launch_bounds(256,4) caps VGPR 128 (pass floor ~104 with unroll-2 prefetch).
// Epilogues via 16 KB XOR-swizzled LDS transpose tile (coalesced stores, R7).
__global__ __launch_bounds__(256, 4) void qkv_kernel(
    const bf16* __restrict__ hT,
    const bf16* __restrict__ wqb, const bf16* __restrict__ wkb, const bf16* __restrict__ wvb,
    const float* __restrict__ bq, const float* __restrict__ bk, const float* __restrict__ bv,
    u8* __restrict__ qT8, u8* __restrict__ kT8, u8* __restrict__ v8) {
  int b = blockIdx.x >> 6, i0 = (blockIdx.x & 63) << 6;
  int t = threadIdx.x, w = t >> 6, lane = t & 63, quad = lane >> 4, l15 = lane & 15;
  __shared__ bf16 hl[64 * 264];   // hT tile [64 i][256 c'], pad +8 (33 KB)
  __shared__ __align__(16) u8 ep[16384];  // transpose staging, reused Q -> K -> V
#pragma unroll
  for (int p = 0; p < 8; p++) {
    int u = t + p * 256, r = u >> 5, c16 = u & 31;
    *(bf16x8*)(hl + r * 264 + c16 * 8) =
        *(const bf16x8*)(hT + ((size_t)(b * N_ + i0 + r)) * C_ + c16 * 8);
  }
  __syncthreads();
  int cw0 = w * 64;

  // ================= PASS Q: D rows = c_out, cols = i =================
  {
    f32x4 acc[4][4];
#pragma unroll
    for (int a = 0; a < 4; a++)
#pragma unroll
      for (int bb2 = 0; bb2 < 4; bb2++) acc[a][bb2] = (f32x4){0.f, 0.f, 0.f, 0.f};
#pragma unroll 2
    for (int kc = 0; kc < 8; kc++) {
      bf16x8 hb[4];
#pragma unroll
      for (int it = 0; it < 4; it++)
        hb[it] = *(const bf16x8*)(hl + (it * 16 + l15) * 264 + kc * 32 + quad * 8);
#pragma unroll
      for (int ct = 0; ct < 4; ct++) {
        bf16x8 wf = *(const bf16x8*)(wqb + ((size_t)(cw0 + ct * 16 + l15)) * C_ + kc * 32 + quad * 8);
#pragma unroll
        for (int it = 0; it < 4; it++) acc[ct][it] = MFMA(wf, hb[it], acc[ct][it]);
      }
    }
    // epilogue: pack fp8 -> swizzled LDS [64 i][256 c] -> coalesced store
#pragma unroll
    for (int ct = 0; ct < 4; ct++)
#pragma unroll
      for (int it = 0; it < 4; it++) {
        int c4 = cw0 + ct * 16 + quad * 4;         // 4 consecutive c per lane
        int il = it * 16 + l15;
        f32x4 b4v = *(const f32x4*)(bq + c4);
        float qv[4];
#pragma unroll
        for (int r = 0; r < 4; r++) qv[r] = (acc[ct][it][r] + b4v[r]) * (QSCALE * 4.0f);
        u32 qd = (u32)__builtin_amdgcn_cvt_pk_fp8_f32(qv[0], qv[1], 0, false);
        qd = (u32)__builtin_amdgcn_cvt_pk_fp8_f32(qv[2], qv[3], (int)qd, true);
        *(u32*)(ep + il * 256 + ((((c4 >> 4) ^ (il & 15)) << 4) | (c4 & 12))) = qd;
      }
    __syncthreads();
#pragma unroll
    for (int p = 0; p < 4; p++) {        // 16 KB out, 16B/lane, rows contiguous
      int u = p * 256 + t, il = u >> 4, ch = u & 15;
      *(u32x4*)(qT8 + ((size_t)(b * N_ + i0 + il)) * C_ + ch * 16) =
          *(const u32x4*)(ep + il * 256 + (((ch ^ (il & 15)) << 4)));
    }
    __syncthreads();
  }

  // ================= PASS K: D rows = c_out, cols = i =================
  {
    f32x4 acc[4][4];
#pragma unroll
    for (int a = 0; a < 4; a++)
#pragma unroll
      for (int bb2 = 0; bb2 < 4; bb2++) acc[a][bb2] = (f32x4){0.f, 0.f, 0.f, 0.f};
#pragma unroll 2
    for (int kc = 0; kc < 8; kc++) {
      bf16x8 hb[4];
#pragma unroll
      for (int it = 0; it < 4; it++)
        hb[it] = *(const bf16x8*)(hl + (it * 16 + l15) * 264 + kc * 32 + quad * 8);
#pragma unroll
      for (int ct = 0; ct < 4; ct++) {
        bf16x8 wf = *(const bf16x8*)(wkb + ((size_t)(cw0 + ct * 16 + l15)) * C_ + kc * 32 + quad * 8);
#pragma unroll
        for (int it = 0; it < 4; it++) acc[ct][it] = MFMA(wf, hb[it], acc[ct][it]);
      }
    }
#pragma unroll
    for (int ct = 0; ct < 4; ct++)
#pragma unroll
      for (int it = 0; it < 4; it++) {
        int c4 = cw0 + ct * 16 + quad * 4;
        int il = it * 16 + l15;
        f32x4 b4v = *(const f32x4*)(bk + c4);
        float kv[4];
#pragma unroll
        for (int r = 0; r < 4; r++) kv[r] = (acc[ct][it][r] + b4v[r]) * 0.25f;
        u32 kd = (u32)__builtin_amdgcn_cvt_pk_fp8_f32(kv[0], kv[1], 0, false);
        kd = (u32)__builtin_amdgcn_cvt_pk_fp8_f32(kv[2], kv[3], (int)kd, true);
        *(u32*)(ep + il * 256 + ((((c4 >> 4) ^ (il & 15)) << 4) | (c4 & 12))) = kd;
      }
    __syncthreads();
#pragma unroll
    for (int p = 0; p < 4; p++) {
      int u = p * 256 + t, il = u >> 4, ch = u & 15;
      *(u32x4*)(kT8 + ((size_t)(b * N_ + i0 + il)) * C_ + ch * 16) =
          *(const u32x4*)(ep + il * 256 + (((ch ^ (il & 15)) << 4)));
    }
  }

  // ================= PASS V: D rows = i, cols = c_out =================
  {
    f32x4 acc[4][4];                      // acc[it][ct]
#pragma unroll
    for (int a = 0; a < 4; a++)
#pragma unroll
      for (int bb2 = 0; bb2 < 4; bb2++) acc[a][bb2] = (f32x4){0.f, 0.f, 0.f, 0.f};
#pragma unroll 2
    for (int kc = 0; kc < 8; kc++) {
      bf16x8 hb[4];
#pragma unroll
      for (int it = 0; it < 4; it++)
        hb[it] = *(const bf16x8*)(hl + (it * 16 + l15) * 264 + kc * 32 + quad * 8);
#pragma unroll
      for (int ct = 0; ct < 4; ct++) {
        bf16x8 wf = *(const bf16x8*)(wvb + ((size_t)(cw0 + ct * 16 + l15)) * C_ + kc * 32 + quad * 8);
#pragma unroll
        for (int it = 0; it < 4; it++) acc[it][ct] = MFMA(hb[it], wf, acc[it][ct]);
      }
    }
    __syncthreads();                      // all K readouts of ep done
    // epilogue: pack fp8 -> swizzled LDS [256 c][64 i] -> 64B-segment store
#pragma unroll
    for (int it = 0; it < 4; it++)
#pragma unroll
      for (int ct = 0; ct < 4; ct++) {
        int cl = cw0 + ct * 16 + l15;
        float bvc = bv[cl];
        float vv4[4];
#pragma unroll
        for (int r = 0; r < 4; r++) vv4[r] = acc[it][ct][r] + bvc;
        u32 vd = (u32)__builtin_amdgcn_cvt_pk_fp8_f32(vv4[0], vv4[1], 0, false);
        vd = (u32)__builtin_amdgcn_cvt_pk_fp8_f32(vv4[2], vv4[3], (int)vd, true);
        *(u32*)(ep + cl * 64 + ((((it ^ (cl & 3)) << 4)) | (quad * 4))) = vd;
      }
    __syncthreads();
#pragma unroll
    for (int p = 0; p < 4; p++) {        // 16 KB out, 16B/lane, 64B c-row segments
      int u = p * 256 + t, cl = u >> 2, io = u & 3;
      *(u32x4*)(v8 + ((size_t)(b * C_ + cl)) * N_ + i0 + io * 16) =
          *(const u32x4*)(ep + cl * 64 + (((io ^ (cl & 3)) << 4)));
    }
  }
}

// ---------------------------------------------------------------- flash attention, fp8 MX MFMA 32x32x64, 64-key tiles, split-K=2
// FROZEN at R6 (82.5 us measured): T15 double-pipeline (PV delayed one tile),
// vmcnt(8) counted waits, permlane32 C->A, popcount stagger (neutral, kept).
// REGISTER BUDGET IS EXACTLY FULL: of[8]=128 AGPR + 128 VGPR = 256 unified
// regs/wave.  R5's extra cross-iteration state spilled (+15MB HBM, 128us);
// R3's (256,3) spilled of[] itself (1.98GB, 470us).
// SQ_LDS_BANK_CONFLICT ~= 16/DMA is structural to global_load_lds -- ignore.
__global__ __launch_bounds__(256, 2) void attn_kernel(
    const u8* __restrict__ qT8, const u8* __restrict__ kT8, const u8* __restrict__ v8,
    bf16* __restrict__ zn0, bf16* __restrict__ znR, float* __restrict__ lsum) {
  constexpr int NJT = 32;                 // 2048 keys / 64 per split
  int blk = blockIdx.x;
  int sp = blk >> 8;                      // 0..1 key split
  int b = blk & 7;                        // XCD-pinned batch
  int i0 = ((blk >> 3) & 31) << 7;        // 128 q-rows per block
  int t = threadIdx.x, w = t >> 6, lane = t & 63;
  int r31 = lane & 31, h = lane >> 5;
  __shared__ __align__(16) u8 lds8[4 * 16384];  // kb0 | kb1 | vb0 | vb1

  int iw = i0 + w * 32;                   // this wave's 32 query rows
  // Q as B-frag (col i = r31, k = c, 32B per MFMA)
  const u8* qrow = qT8 + ((size_t)(b * N_ + iw + r31)) * C_ + h * 32;
  i32x8 qB[4];
#pragma unroll
  for (int m = 0; m < 4; m++) qB[m] = *(const i32x8*)(qrow + m * 64);

  f32x16 of[8];
#pragma unroll
  for (int ct = 0; ct < 8; ct++)
#pragma unroll
    for (int e = 0; e < 16; e++) of[ct][e] = 0.f;
  float lacc = 0.f;

  int ks = r31 & 7;                       // K-read swizzle
  // DMA lane decode (loop-invariant)
  int kr_off = lane >> 4;                 // row within K issue (4 rows/KB)
  int kc_pos = lane & 15;                 // dest chunk
  int vr_off = lane >> 2;                 // row within V issue (16 rows/KB)
  int vc_pos = lane & 3;
  int spBase = sp * 2048;

  auto stageK = [&](int jts, u8* kb) {
    int j0s = spBase + jts * 64;
#pragma unroll
    for (int p = 0; p < 4; p++) {         // kT: 16 x 1KB issues, 4 per wave
      int idx = w * 4 + p;
      int r = idx * 4 + kr_off;
      int chunk = kc_pos ^ (r & 7);
      GLOAD_LDS16(kT8 + ((size_t)(b * N_ + j0s + r)) * C_ + chunk * 16, kb + idx * 1024);
    }
  };
  auto stageV = [&](int jts, u8* vb) {
    int j0s = spBase + jts * 64;
#pragma unroll
    for (int p = 0; p < 4; p++) {         // v: 16 x 1KB issues, 4 per wave
      int idx = w * 4 + p;
      int c = idx * 16 + vr_off;
      int chunk = vc_pos ^ ((c >> 1) & 3);
      GLOAD_LDS16(v8 + ((size_t)(b * C_ + c)) * N_ + j0s + chunk * 16, vb + idx * 1024);
    }
  };

  stageK(0, lds8);                        // prologue: K(0), V(0) in flight
  stageV(0, lds8 + 32768);

  // anti-phase stagger (measured neutral, kept): odd-popcount blocks start late
  if (__popc(blk) & 1) __builtin_amdgcn_s_sleep(48);   // ~3072 cyc

  i32x8 pPrev;                            // fp8-packed P of tile jt-1

  for (int jt = 0; jt < NJT; jt++) {
    stageK(jt < NJT - 1 ? jt + 1 : jt, lds8 + (((jt + 1) & 1) << 14));
    asm volatile("s_waitcnt vmcnt(8)" ::: "memory");  // own K(jt) landed
    __builtin_amdgcn_s_barrier();         // B: everyone's K(jt) + V(jt-1) in LDS
    const u8* kTl = lds8 + ((jt & 1) << 14);
    const u8* vbp = lds8 + 32768 + (((jt + 1) & 1) << 14);  // vb[(jt-1)&1]

    // ---- QK^T g0: S^T rows j=r31, C-init = -PBIAS
    f32x16 st0;
#pragma unroll
    for (int e = 0; e < 16; e++) st0[e] = -PBIAS;
    {
      const u8* krow = kTl + r31 * 256;
      __builtin_amdgcn_s_setprio(1);
#pragma unroll
      for (int m = 0; m < 4; m++) {
        int cd = m * 4 + h * 2;
        union { i32x8 v; u32x4 h4[2]; } kf;
        kf.h4[0] = *(const u32x4*)(krow + ((cd ^ ks) * 16));
        kf.h4[1] = *(const u32x4*)(krow + (((cd + 1) ^ ks) * 16));
        st0 = MFMAS(kf.v, qB[m], st0);
      }
    }
    // ---- PV(jt-1): independent of st0 chain & softmax -> fills matrix pipe
    if (jt) {
#pragma unroll
      for (int ct = 0; ct < 8; ct++) {
        int c = ct * 32 + r31;
        int vs = (c >> 1) & 3;
        const u8* vrow = vbp + c * 64;
        union { i32x8 v; u32x4 h4[2]; } vB;
        vB.h4[0] = *(const u32x4*)(vrow + (((2 * h) ^ vs) * 16));
        vB.h4[1] = *(const u32x4*)(vrow + (((2 * h + 1) ^ vs) * 16));
        of[ct] = MFMAS(pPrev, vB.v, of[ct]);
      }
    }
    __builtin_amdgcn_s_setprio(0);
    // ---- softmax g0 (runs while PV MFMAs crunch)
    u32 PG0[4], PG1[4];
#pragma unroll
    for (int b4 = 0; b4 < 4; b4++) {
      float p0 = __builtin_amdgcn_exp2f(st0[b4 * 4 + 0]);
      float p1 = __builtin_amdgcn_exp2f(st0[b4 * 4 + 1]);
      float p2 = __builtin_amdgcn_exp2f(st0[b4 * 4 + 2]);
      float p3 = __builtin_amdgcn_exp2f(st0[b4 * 4 + 3]);
      lacc += (p0 + p1) + (p2 + p3);
      u32 d = (u32)__builtin_amdgcn_cvt_pk_fp8_f32(p0, p1, 0, false);
      d = (u32)__builtin_amdgcn_cvt_pk_fp8_f32(p2, p3, (int)d, true);
      PG0[b4] = d;
    }
    // ---- QK^T g1
    f32x16 st1;
#pragma unroll
    for (int e = 0; e < 16; e++) st1[e] = -PBIAS;
    {
      const u8* krow = kTl + (32 + r31) * 256;
      __builtin_amdgcn_s_setprio(1);
#pragma unroll
      for (int m = 0; m < 4; m++) {
        int cd = m * 4 + h * 2;
        union { i32x8 v; u32x4 h4[2]; } kf;
        kf.h4[0] = *(const u32x4*)(krow + ((cd ^ ks) * 16));
        kf.h4[1] = *(const u32x4*)(krow + (((cd + 1) ^ ks) * 16));
        st1 = MFMAS(kf.v, qB[m], st1);
      }
      __builtin_amdgcn_s_setprio(0);
    }
    // ---- softmax g1
#pragma unroll
    for (int b4 = 0; b4 < 4; b4++) {
      float p0 = __builtin_amdgcn_exp2f(st1[b4 * 4 + 0]);
      float p1 = __builtin_amdgcn_exp2f(st1[b4 * 4 + 1]);
      float p2 = __builtin_amdgcn_exp2f(st1[b4 * 4 + 2]);
      float p3 = __builtin_amdgcn_exp2f(st1[b4 * 4 + 3]);
      lacc += (p0 + p1) + (p2 + p3);
      u32 d = (u32)__builtin_amdgcn_cvt_pk_fp8_f32(p0, p1, 0, false);
      d = (u32)__builtin_amdgcn_cvt_pk_fp8_f32(p2, p3, (int)d, true);
      PG1[b4] = d;
    }
    // ---- C->A exchange into pPrev (old pPrev already consumed by PV above)
    // permlane32_swap(PG0, PG1):
    //   rr[0]: lanes<32 own PG0 (j=8b4+0..3)    | lanes>=32 partner PG1 (j=32+8b4+0..3)
    //   rr[1]: lanes<32 partner PG0 (j=8b4+4..7)| lanes>=32 own PG1 (j=32+8b4+4..7)
#pragma unroll
    for (int b4 = 0; b4 < 4; b4++) {
      u32x2 rr = __builtin_amdgcn_permlane32_swap(PG0[b4], PG1[b4], false, false);
      pPrev[2 * b4]     = (int)rr[0];
      pPrev[2 * b4 + 1] = (int)rr[1];
    }

    __builtin_amdgcn_s_barrier();         // C: all reads of kb[jt&1], vb[(jt-1)&1] done
    if (jt < NJT - 1) stageV(jt + 1, lds8 + 32768 + (((jt + 1) & 1) << 14));
  }

  // ---- epilogue: final PV(NJT-1)
  asm volatile("s_waitcnt vmcnt(0)" ::: "memory");
  __builtin_amdgcn_s_barrier();           // everyone's V(NJT-1) landed
  {
    const u8* vbp = lds8 + 32768 + (((NJT - 1) & 1) << 14);
#pragma unroll
    for (int ct = 0; ct < 8; ct++) {
      int c = ct * 32 + r31;
      int vs = (c >> 1) & 3;
      const u8* vrow = vbp + c * 64;
      union { i32x8 v; u32x4 h4[2]; } vB;
      vB.h4[0] = *(const u32x4*)(vrow + (((2 * h) ^ vs) * 16));
      vB.h4[1] = *(const u32x4*)(vrow + (((2 * h + 1) ^ vs) * 16));
      of[ct] = MFMAS(pPrev, vB.v, of[ct]);
    }
  }

  // ---- write partials: zNum [sp][b][c][i] bf16, lsum [sp][b][i] f32
  lacc += __shfl_xor(lacc, 32);           // full key-split sum (once per kernel)
  if (h == 0)
    lsum[((size_t)(sp * 8 + b)) * N_ + iw + r31] = lacc;
  bf16* zn = (sp == 0) ? zn0 : znR;
#pragma unroll
  for (int ct = 0; ct < 8; ct++) {
    int c = ct * 32 + r31;
#pragma unroll
    for (int g = 0; g < 4; g++) {
      bf16x4 zv;
#pragma unroll
      for (int e = 0; e < 4; e++) zv[e] = (bf16)of[ct][g * 4 + e];
      int i4 = iw + 8 * g + 4 * h;        // rows i = e + 8g + 4h
      *(bf16x4*)(zn + ((size_t)(b * C_ + c)) * N_ + i4) = zv;  // 8B packed
    }
  }
}

// ---------------------------------------------------------------- combine partials + O-proj + bias + skip
// zl pad 266: staging writes 2-way banked; GEMM reads conflict-free.
__global__ __launch_bounds__(256) void combine_kernel(
    const bf16* __restrict__ zn0, const bf16* __restrict__ znR,
    const float* __restrict__ lsum,
    const bf16* __restrict__ wob, const float* __restrict__ bo,
    const float* __restrict__ x, float* __restrict__ out) {
  int b = blockIdx.x >> 6, i0 = (blockIdx.x & 63) << 6;
  int t = threadIdx.x, w = t >> 6, lane = t & 63, quad = lane >> 4, l15 = lane & 15;
  __shared__ bf16 zl[64 * 266];         // zT tile [64 i][256 c], pad +10
  __shared__ float linv[64];

  if (t < 64) {
    size_t ii = (size_t)b * N_ + i0 + t;
    linv[t] = 1.f / (lsum[ii] + lsum[ii + (size_t)8 * N_]);
  }
  __syncthreads();

#pragma unroll
  for (int p = 0; p < 16; p++) {        // 256 c x 16 i4-chunks; coalesced 8B reads
    int u = t + p * 256, c = u >> 4, ii = (u & 15) * 4;
    size_t base = ((size_t)(b * C_ + c)) * N_ + i0 + ii;
    bf16x4 z0 = *(const bf16x4*)(zn0 + base);
    bf16x4 z1 = *(const bf16x4*)(znR + base);
#pragma unroll
    for (int e = 0; e < 4; e++)
      zl[(ii + e) * 266 + c] = (bf16)(((float)z0[e] + (float)z1[e]) * linv[ii + e]);
  }
  __syncthreads();

  f32x4 oa[4][4];
#pragma unroll
  for (int a = 0; a < 4; a++)
#pragma unroll
    for (int bb2 = 0; bb2 < 4; bb2++) oa[a][bb2] = (f32x4){0.f, 0.f, 0.f, 0.f};
  for (int kc = 0; kc < 8; kc++) {
    bf16x8 za[4];
#pragma unroll
    for (int it = 0; it < 4; it++)
      za[it] = *(const bf16x8*)(zl + (it * 16 + l15) * 266 + kc * 32 + quad * 8);
#pragma unroll
    for (int ctl = 0; ctl < 4; ctl++) {
      bf16x8 wf = *(const bf16x8*)(wob + ((size_t)(w * 64 + ctl * 16 + l15)) * C_ + kc * 32 + quad * 8);
#pragma unroll
      for (int it = 0; it < 4; it++) oa[ctl][it] = MFMA(za[it], wf, oa[ctl][it]);
    }
  }
#pragma unroll
  for (int ctl = 0; ctl < 4; ctl++)
#pragma unroll
    for (int it = 0; it < 4; it++) {
      int c = w * 64 + ctl * 16 + l15;
      size_t base = ((size_t)(b * C_ + c)) * N_ + i0 + it * 16 + quad * 4;
      f32x4 xs = *(const f32x4*)(x + base);
      float boc = bo[c];
      f32x4 o4;
#pragma unroll
      for (int r = 0; r < 4; r++) o4[r] = oa[ctl][it][r] + boc + xs[r];
      *(f32x4*)(out + base) = o4;     // coalesced 16B fp32 store, skip fused
    }
}

// ---------------------------------------------------------------- launch
extern "C" void kernel_launch(void* const* d_in, const int* in_sizes, int n_in,
                              void* d_out, int out_size, void* d_ws, size_t ws_size,
                              hipStream_t stream) {
  const float* x   = (const float*)d_in[0];
  const float* gsc = (const float*)d_in[1];
  const float* gbi = (const float*)d_in[2];
  const float* wq  = (const float*)d_in[3];
  const float* bq  = (const float*)d_in[4];
  const float* wk  = (const float*)d_in[5];
  const float* bk  = (const float*)d_in[6];
  const float* wv  = (const float*)d_in[7];
  const float* bv  = (const float*)d_in[8];
  const float* wo  = (const float*)d_in[9];
  const float* bo  = (const float*)d_in[10];

  char* ws = (char*)d_ws;
  bf16* hT   = (bf16*)(ws + HT_OFF);
  u8*   qT8  = (u8*)(ws + QT_OFF);
  u8*   kT8  = (u8*)(ws + KT_OFF);
  u8*   v8   = (u8*)(ws + V_OFF);
  bf16* wqb  = (bf16*)(ws + WQ_OFF);
  bf16* wkb  = (bf16*)(ws + WK_OFF);
  bf16* wvb  = (bf16*)(ws + WV_OFF);
  bf16* wob  = (bf16*)(ws + WO_OFF);
  float* lsum = (float*)(ws + LS_OFF);
  bf16* zn0  = (bf16*)(ws + HT_OFF);     // partial 0 reuses hT (dead after qkv)
  bf16* znR  = (bf16*)(ws + ZN2_OFF);    // partial 1

  gn_kernel<<<256, 512, 0, stream>>>(x, gsc, gbi, hT, wq, wk, wv, wo, wqb, wkb, wvb, wob);
  qkv_kernel<<<512, 256, 0, stream>>>(hT, wqb, wkb, wvb, bq, bk, bv, qT8, kT8, v8);
  attn_kernel<<<512, 256, 0, stream>>>(qT8, kT8, v8, zn0, znR, lsum);
  combine_kernel<<<512, 256, 0, stream>>>(zn0, znR, lsum, wob, bo, x, (float*)d_out);
}